// Round 3
// baseline (3016.217 us; speedup 1.0000x reference)
//
#include <hip/hip_runtime.h>

// Problem sizes (fixed)
#define NR 120000   // occupied voxels
#define CI 32
#define CO 64
#define KK 27

// async global->LDS, 16B per lane. LDS dest must be wave-uniform-base + lane*16.
#define GLOAD_LDS16(g, l) __builtin_amdgcn_global_load_lds( \
    (const __attribute__((address_space(1))) unsigned int*)(g), \
    (__attribute__((address_space(3))) unsigned int*)(l), 16, 0, 0)

// ---------------------------------------------------------------------------
// K1: conv1 (32->64, 27 offsets) + classifier/mask + compaction.
// 256 thr = 4 waves. Tile: dq=t&15 -> 4 channels, rq=t>>4 -> 8 rows (rp*16+rq).
// Double-buffered gs (async DMA) + double-buffered Ws -> ONE barrier per k.
// LDS: gs 32K + Ws 16K + sl 0.5K = 48.5K -> 3 blocks/CU.
// Staging: slot=p*256+t, r=p*32+(t>>3), q=t&7; LDS linear in slot (DMA rule),
// global source quad pre-swizzled by q^(r&7); reads use same XOR -> no conflicts.
// ---------------------------------------------------------------------------
__global__ __launch_bounds__(256, 2)
void k_conv1(const float* __restrict__ xF, const float* __restrict__ gum,
             const int* __restrict__ nbr, const float* __restrict__ Wch,
             const float* __restrict__ bch, const float* __restrict__ Wcls,
             const float* __restrict__ bcls, const float* __restrict__ zrowX,
             float* __restrict__ x1m, int* __restrict__ sids,
             int* __restrict__ cnt, float* __restrict__ outp)
{
    __shared__ float gs[2 * 128 * CI];      // 32 KB
    __shared__ float Ws[2][CI * CO];        // 16 KB
    __shared__ int   sl[128];
    __shared__ int   scnt, sbase;

    const int t    = threadIdx.x;
    const int dq   = t & 15;
    const int rq   = t >> 4;
    const int rq7  = rq & 7;
    const int dq4  = dq * 4;
    const int sr   = t >> 3;   // staging row within 32-row chunk
    const int sq   = t & 7;    // staging quad
    const int row0 = blockIdx.x * 128;

    if (t == 0) scnt = 0;

    // --- prologue: k=0 DMA, W[0]->LDS, prefetch k=1 ids and W[1] ---
    int jr[4];
#pragma unroll
    for (int pp = 0; pp < 4; ++pp) {
        int i = row0 + pp * 32 + sr;
        jr[pp] = (i < NR) ? nbr[i * KK] : NR;
    }
#pragma unroll
    for (int pp = 0; pp < 4; ++pp) {
        int r = pp * 32 + sr;
        const float* gsrc = (jr[pp] < NR) ? (xF + (size_t)jr[pp] * CI) : zrowX;
        GLOAD_LDS16(gsrc + ((sq ^ (r & 7)) << 2), &gs[(pp * 256 + t) * 4]);
    }
    {
        const float4* Wk = (const float4*)Wch;
        float4 a0 = Wk[t], a1 = Wk[t + 256];
        float4* Wv = (float4*)&Ws[0][0];
        Wv[t] = a0; Wv[t + 256] = a1;
    }
#pragma unroll
    for (int pp = 0; pp < 4; ++pp) {
        int i = row0 + pp * 32 + sr;
        jr[pp] = (i < NR) ? nbr[i * KK + 1] : NR;
    }
    float4 wr0, wr1;
    {
        const float4* Wk = (const float4*)(Wch + CI * CO);
        wr0 = Wk[t]; wr1 = Wk[t + 256];
    }

    const float4 bq = ((const float4*)bch)[dq];
    float4 acc[8];
#pragma unroll
    for (int rp = 0; rp < 8; ++rp) acc[rp] = bq;

    float wcA[4], wcB[4];
#pragma unroll
    for (int c = 0; c < 4; ++c) {
        wcA[c] = Wcls[(dq4 + c) * 2];
        wcB[c] = Wcls[(dq4 + c) * 2 + 1];
    }
    const float b0 = bcls[0], b1 = bcls[1];

    int gso = 0, wp = 0;
    __syncthreads();   // gs buf0 + Ws[0] ready (vmcnt+lgkm drained by syncthreads)

#pragma unroll 1
    for (int k = 0; k < KK; ++k) {
        if (k < KK - 1) {
            // issue next tile's DMA into other buffer (hides under compute)
#pragma unroll
            for (int pp = 0; pp < 4; ++pp) {
                int r = pp * 32 + sr;
                const float* gsrc = (jr[pp] < NR) ? (xF + (size_t)jr[pp] * CI) : zrowX;
                GLOAD_LDS16(gsrc + ((sq ^ (r & 7)) << 2),
                            &gs[(gso ^ (128 * CI)) + (pp * 256 + t) * 4]);
            }
            // write W[k+1] (prefetched last iter) into other Ws buffer
            float4* Wv = (float4*)&Ws[wp ^ 1][0];
            Wv[t] = wr0; Wv[t + 256] = wr1;
        }
        if (k < KK - 2) {
            // prefetch ids(k+2) and W[k+2]
#pragma unroll
            for (int pp = 0; pp < 4; ++pp) {
                int i = row0 + pp * 32 + sr;
                jr[pp] = (i < NR) ? nbr[i * KK + k + 2] : NR;
            }
            const float4* Wk = (const float4*)(Wch + (size_t)(k + 2) * CI * CO);
            wr0 = Wk[t]; wr1 = Wk[t + 256];
        }
        // compute k
        const float* gsb = &gs[gso];
        const float* wsb = &Ws[wp][0];
#pragma unroll
        for (int cq = 0; cq < CI / 4; ++cq) {
            float4 w0 = *(const float4*)&wsb[(cq * 4 + 0) * CO + dq4];
            float4 w1 = *(const float4*)&wsb[(cq * 4 + 1) * CO + dq4];
            float4 w2 = *(const float4*)&wsb[(cq * 4 + 2) * CO + dq4];
            float4 w3 = *(const float4*)&wsb[(cq * 4 + 3) * CO + dq4];
            const int cs = ((cq ^ rq7) << 2);
#pragma unroll
            for (int rp = 0; rp < 8; ++rp) {
                float4 g = *(const float4*)&gsb[(rp * 16 + rq) * CI + cs];
                acc[rp].x += g.x * w0.x + g.y * w1.x + g.z * w2.x + g.w * w3.x;
                acc[rp].y += g.x * w0.y + g.y * w1.y + g.z * w2.y + g.w * w3.y;
                acc[rp].z += g.x * w0.z + g.y * w1.z + g.z * w2.z + g.w * w3.z;
                acc[rp].w += g.x * w0.w + g.y * w1.w + g.z * w2.w + g.w * w3.w;
            }
        }
        __syncthreads();   // drains DMA (vmcnt0) + orders Ws write for next iter
        gso ^= (128 * CI); wp ^= 1;
    }

    // epilogue: classifier (all 16 lanes end with the full sums), mask, writes
#pragma unroll
    for (int rp = 0; rp < 8; ++rp) {
        float4 a = acc[rp];
        float p0 = a.x * wcA[0] + a.y * wcA[1] + a.z * wcA[2] + a.w * wcA[3];
        float p1 = a.x * wcB[0] + a.y * wcB[1] + a.z * wcB[2] + a.w * wcB[3];
#pragma unroll
        for (int off = 1; off < 16; off <<= 1) {
            p0 += __shfl_xor(p0, off, 64);
            p1 += __shfl_xor(p1, off, 64);
        }
        int i = row0 + rp * 16 + rq;
        if (i < NR) {
            float z0 = p0 + b0 + gum[2 * i];
            float z1 = p1 + b1 + gum[2 * i + 1];
            bool m = (z0 >= z1);   // argmax tie -> index 0 -> strong
            ((float4*)(outp + (size_t)i * CO))[dq] =
                make_float4(2.f * a.x, 2.f * a.y, 2.f * a.z, 2.f * a.w);
            float4 xm = m ? a : make_float4(0.f, 0.f, 0.f, 0.f);
            ((float4*)(x1m + (size_t)i * CO))[dq] = xm;
            if (dq == 0 && m) { int pos = atomicAdd(&scnt, 1); sl[pos] = i; }
        }
    }
    __syncthreads();
    if (t == 0) sbase = atomicAdd(cnt, scnt);
    __syncthreads();
    if (t < scnt) sids[sbase + t] = sl[t];
}

// ---------------------------------------------------------------------------
// K2: conv2 (64->64) over compacted strong rows, gathering masked x1m
// (weak rows are zeros -> no mask load needed). 64 rows/block.
// LDS: gs dbuf 32K + Ws 16K = 48.5K -> 3 blocks/CU. Two barriers per k
// (single-buffered Ws rewritten after compute).
// Staging: slot=p*256+t, r=p*16+rq, q=dq; swizzle q^rq both sides.
// ---------------------------------------------------------------------------
__global__ __launch_bounds__(256, 2)
void k_conv2(const float* __restrict__ x1m, const int* __restrict__ nbr,
             const float* __restrict__ Wdw, const float* __restrict__ bdw,
             const int* __restrict__ sids, const int* __restrict__ cnt,
             const float* __restrict__ zrow1, float* __restrict__ outp)
{
    const int nstrong = *cnt;
    const int row0 = blockIdx.x * 64;
    if (row0 >= nstrong) return;

    __shared__ float gs[2 * 64 * CO];   // 32 KB
    __shared__ float Ws[CO * CO];       // 16 KB

    const int t   = threadIdx.x;
    const int dq  = t & 15;
    const int rq  = t >> 4;
    const int dq4 = dq * 4;

    int ssid[4];
#pragma unroll
    for (int pp = 0; pp < 4; ++pp) {
        int rr = row0 + pp * 16 + rq;
        ssid[pp] = (rr < nstrong) ? sids[rr] : -1;
    }

    int jr[4];
#pragma unroll
    for (int pp = 0; pp < 4; ++pp)
        jr[pp] = (ssid[pp] >= 0) ? nbr[(size_t)ssid[pp] * KK] : NR;
#pragma unroll
    for (int pp = 0; pp < 4; ++pp) {
        const float* gsrc = (jr[pp] < NR) ? (x1m + (size_t)jr[pp] * CO) : zrow1;
        GLOAD_LDS16(gsrc + ((dq ^ rq) << 2), &gs[(pp * 256 + t) * 4]);
    }
    {
        const float4* Wk = (const float4*)Wdw;
        float4 a0 = Wk[t], a1 = Wk[t + 256], a2 = Wk[t + 512], a3 = Wk[t + 768];
        float4* Wv = (float4*)Ws;
        Wv[t] = a0; Wv[t + 256] = a1; Wv[t + 512] = a2; Wv[t + 768] = a3;
    }
#pragma unroll
    for (int pp = 0; pp < 4; ++pp)
        jr[pp] = (ssid[pp] >= 0) ? nbr[(size_t)ssid[pp] * KK + 1] : NR;

    float4 acc[4];
#pragma unroll
    for (int rp = 0; rp < 4; ++rp) acc[rp] = make_float4(0.f, 0.f, 0.f, 0.f);

    float4 wr0, wr1, wr2, wr3;
    int gso = 0;
    __syncthreads();

#pragma unroll 1
    for (int k = 0; k < KK; ++k) {
        if (k < KK - 1) {
#pragma unroll
            for (int pp = 0; pp < 4; ++pp) {
                const float* gsrc = (jr[pp] < NR) ? (x1m + (size_t)jr[pp] * CO) : zrow1;
                GLOAD_LDS16(gsrc + ((dq ^ rq) << 2),
                            &gs[(gso ^ (64 * CO)) + (pp * 256 + t) * 4]);
            }
            const float4* Wk = (const float4*)(Wdw + (size_t)(k + 1) * CO * CO);
            wr0 = Wk[t]; wr1 = Wk[t + 256]; wr2 = Wk[t + 512]; wr3 = Wk[t + 768];
        }
        if (k < KK - 2) {
#pragma unroll
            for (int pp = 0; pp < 4; ++pp)
                jr[pp] = (ssid[pp] >= 0) ? nbr[(size_t)ssid[pp] * KK + k + 2] : NR;
        }
        const float* gsb = &gs[gso];
#pragma unroll
        for (int cq = 0; cq < CO / 4; ++cq) {
            float4 w0 = *(const float4*)&Ws[(cq * 4 + 0) * CO + dq4];
            float4 w1 = *(const float4*)&Ws[(cq * 4 + 1) * CO + dq4];
            float4 w2 = *(const float4*)&Ws[(cq * 4 + 2) * CO + dq4];
            float4 w3 = *(const float4*)&Ws[(cq * 4 + 3) * CO + dq4];
            const int cs = ((cq ^ rq) << 2);
#pragma unroll
            for (int rp = 0; rp < 4; ++rp) {
                float4 g = *(const float4*)&gsb[(rp * 16 + rq) * CO + cs];
                acc[rp].x += g.x * w0.x + g.y * w1.x + g.z * w2.x + g.w * w3.x;
                acc[rp].y += g.x * w0.y + g.y * w1.y + g.z * w2.y + g.w * w3.y;
                acc[rp].z += g.x * w0.z + g.y * w1.z + g.z * w2.z + g.w * w3.z;
                acc[rp].w += g.x * w0.w + g.y * w1.w + g.z * w2.w + g.w * w3.w;
            }
        }
        __syncthreads();   // done reading Ws + gs[gso]; DMA drained
        if (k < KK - 1) {
            float4* Wv = (float4*)Ws;
            Wv[t] = wr0; Wv[t + 256] = wr1; Wv[t + 512] = wr2; Wv[t + 768] = wr3;
            __syncthreads();
        }
        gso ^= (64 * CO);
    }

    const float4 bq = ((const float4*)bdw)[dq];
#pragma unroll
    for (int rp = 0; rp < 4; ++rp) {
        int rr = row0 + rp * 16 + rq;
        if (rr < nstrong) {
            int sid = sids[rr];
            float4 xv = ((const float4*)(x1m + (size_t)sid * CO))[dq];
            float4 a = acc[rp];
            ((float4*)(outp + (size_t)sid * CO))[dq] =
                make_float4(a.x + bq.x + xv.x, a.y + bq.y + xv.y,
                            a.z + bq.z + xv.z, a.w + bq.w + xv.w);
        }
    }
}

// ---------------------------------------------------------------------------
extern "C" void kernel_launch(void* const* d_in, const int* in_sizes, int n_in,
                              void* d_out, int out_size, void* d_ws, size_t ws_size,
                              hipStream_t stream)
{
    const float* xF   = (const float*)d_in[0];
    const float* gum  = (const float*)d_in[1];
    const int*   nbr  = (const int*)d_in[2];
    const float* Wch  = (const float*)d_in[3];
    const float* bch  = (const float*)d_in[4];
    const float* Wcls = (const float*)d_in[5];
    const float* bcls = (const float*)d_in[6];
    const float* Wdw  = (const float*)d_in[7];
    const float* bdw  = (const float*)d_in[8];
    // d_in[9] = th (unused by the forward computation)

    float* outp = (float*)d_out;
    char*  ws   = (char*)d_ws;

    // ws layout: [0,128) zrowX | [128,384) zrow1 | [384,388) cnt |
    //            [512, 512+480000) sids | then x1m (N*64 f32)
    float* zrowX = (float*)(ws);
    float* zrow1 = (float*)(ws + 128);
    int*   cnt   = (int*)(ws + 384);
    int*   sids  = (int*)(ws + 512);
    float* x1m   = (float*)(ws + 512 + (size_t)NR * 4);

    hipMemsetAsync(ws, 0, 512, stream);   // zero rows + cnt

    hipLaunchKernelGGL(k_conv1, dim3((NR + 127) / 128), dim3(256), 0, stream,
                       xF, gum, nbr, Wch, bch, Wcls, bcls, zrowX,
                       x1m, sids, cnt, outp);
    hipLaunchKernelGGL(k_conv2, dim3((NR + 63) / 64), dim3(256), 0, stream,
                       x1m, nbr, Wdw, bdw, sids, cnt, zrow1, outp);
}

// Round 7
// 1781.358 us; speedup vs baseline: 1.6932x; 1.6932x over previous
//
#include <hip/hip_runtime.h>

// Problem sizes (fixed)
#define NR 120000   // occupied voxels
#define CI 32
#define CO 64
#define KK 27

// async global->LDS, 16B per lane. LDS dest must be wave-uniform base + lane*16.
#define GLOAD_LDS16(g, l) __builtin_amdgcn_global_load_lds( \
    (const __attribute__((address_space(1))) unsigned int*)(g), \
    (__attribute__((address_space(3))) unsigned int*)(l), 16, 0, 0)

// ---------------------------------------------------------------------------
// K1: conv1 (32->64, 27 offsets) + classifier/mask + compaction.
// 256 thr = 4 waves. dq=t&15 -> 4 channels, rq=t>>4 -> 8 rows (rp*16+rq).
// Double-buffered gs (async global_load_lds DMA) + double-buffered Ws ->
// ONE barrier per k. LDS ~49.7 KB -> 3 blocks/CU.
// Invalid-neighbor lanes read from a 64-row spread zero buffer (zbufX) to
// avoid all lanes hammering one cache line through the DMA path.
// ---------------------------------------------------------------------------
__global__ __launch_bounds__(256, 2)
void k_conv1(const float* __restrict__ xF, const float* __restrict__ gum,
             const int* __restrict__ nbr, const float* __restrict__ Wch,
             const float* __restrict__ bch, const float* __restrict__ Wcls,
             const float* __restrict__ bcls, const float* __restrict__ zbufX,
             float* __restrict__ x1m, int* __restrict__ sids,
             int* __restrict__ cnt, float* __restrict__ outp)
{
    __shared__ float gs[2 * 128 * CI];      // 32 KB
    __shared__ float Ws[2][CI * CO];        // 16 KB
    __shared__ int   sl[128];
    __shared__ int   scnt, sbase;

    const int t    = threadIdx.x;
    const int dq   = t & 15;
    const int rq   = t >> 4;
    const int rq7  = rq & 7;
    const int dq4  = dq * 4;
    const int sr   = t >> 3;   // staging row within 32-row chunk
    const int sq   = t & 7;    // staging quad
    const int row0 = blockIdx.x * 128;

    if (t == 0) scnt = 0;

    // --- prologue: k=0 DMA, W[0]->LDS, prefetch k=1 ids and W[1] ---
    int jr[4];
#pragma unroll
    for (int pp = 0; pp < 4; ++pp) {
        int i = row0 + pp * 32 + sr;
        jr[pp] = (i < NR) ? nbr[i * KK] : NR;
    }
#pragma unroll
    for (int pp = 0; pp < 4; ++pp) {
        int r = pp * 32 + sr;
        const float* gsrc = (jr[pp] < NR) ? (xF + (size_t)jr[pp] * CI)
                                          : (zbufX + (r & 63) * CI);
        GLOAD_LDS16(gsrc + ((sq ^ (r & 7)) << 2), &gs[(pp * 256 + t) * 4]);
    }
    {
        const float4* Wk = (const float4*)Wch;
        float4 a0 = Wk[t], a1 = Wk[t + 256];
        float4* Wv = (float4*)&Ws[0][0];
        Wv[t] = a0; Wv[t + 256] = a1;
    }
#pragma unroll
    for (int pp = 0; pp < 4; ++pp) {
        int i = row0 + pp * 32 + sr;
        jr[pp] = (i < NR) ? nbr[i * KK + 1] : NR;
    }
    float4 wr0, wr1;
    {
        const float4* Wk = (const float4*)(Wch + CI * CO);
        wr0 = Wk[t]; wr1 = Wk[t + 256];
    }

    const float4 bq = ((const float4*)bch)[dq];
    float4 acc[8];
#pragma unroll
    for (int rp = 0; rp < 8; ++rp) acc[rp] = bq;

    float wcA[4], wcB[4];
#pragma unroll
    for (int c = 0; c < 4; ++c) {
        wcA[c] = Wcls[(dq4 + c) * 2];
        wcB[c] = Wcls[(dq4 + c) * 2 + 1];
    }
    const float b0 = bcls[0], b1 = bcls[1];

    int gso = 0, wp = 0;
    __syncthreads();   // gs buf0 + Ws[0] ready

#pragma unroll 1
    for (int k = 0; k < KK; ++k) {
        if (k < KK - 1) {
            // issue next tile's DMA into other buffer (hides under compute)
#pragma unroll
            for (int pp = 0; pp < 4; ++pp) {
                int r = pp * 32 + sr;
                const float* gsrc = (jr[pp] < NR) ? (xF + (size_t)jr[pp] * CI)
                                                  : (zbufX + (r & 63) * CI);
                GLOAD_LDS16(gsrc + ((sq ^ (r & 7)) << 2),
                            &gs[(gso ^ (128 * CI)) + (pp * 256 + t) * 4]);
            }
            // write W[k+1] (prefetched last iter) into other Ws buffer
            float4* Wv = (float4*)&Ws[wp ^ 1][0];
            Wv[t] = wr0; Wv[t + 256] = wr1;
        }
        if (k < KK - 2) {
            // prefetch ids(k+2) and W[k+2]
#pragma unroll
            for (int pp = 0; pp < 4; ++pp) {
                int i = row0 + pp * 32 + sr;
                jr[pp] = (i < NR) ? nbr[i * KK + k + 2] : NR;
            }
            const float4* Wk = (const float4*)(Wch + (size_t)(k + 2) * CI * CO);
            wr0 = Wk[t]; wr1 = Wk[t + 256];
        }
        // compute k
        const float* gsb = &gs[gso];
        const float* wsb = &Ws[wp][0];
#pragma unroll
        for (int cq = 0; cq < CI / 4; ++cq) {
            float4 w0 = *(const float4*)&wsb[(cq * 4 + 0) * CO + dq4];
            float4 w1 = *(const float4*)&wsb[(cq * 4 + 1) * CO + dq4];
            float4 w2 = *(const float4*)&wsb[(cq * 4 + 2) * CO + dq4];
            float4 w3 = *(const float4*)&wsb[(cq * 4 + 3) * CO + dq4];
            const int cs = ((cq ^ rq7) << 2);
#pragma unroll
            for (int rp = 0; rp < 8; ++rp) {
                float4 g = *(const float4*)&gsb[(rp * 16 + rq) * CI + cs];
                acc[rp].x += g.x * w0.x + g.y * w1.x + g.z * w2.x + g.w * w3.x;
                acc[rp].y += g.x * w0.y + g.y * w1.y + g.z * w2.y + g.w * w3.y;
                acc[rp].z += g.x * w0.z + g.y * w1.z + g.z * w2.z + g.w * w3.z;
                acc[rp].w += g.x * w0.w + g.y * w1.w + g.z * w2.w + g.w * w3.w;
            }
        }
        __syncthreads();   // drains DMA + orders Ws write for next iter
        gso ^= (128 * CI); wp ^= 1;
    }

    // epilogue: classifier (16-lane shuffle reduce), mask, writes
#pragma unroll
    for (int rp = 0; rp < 8; ++rp) {
        float4 a = acc[rp];
        float p0 = a.x * wcA[0] + a.y * wcA[1] + a.z * wcA[2] + a.w * wcA[3];
        float p1 = a.x * wcB[0] + a.y * wcB[1] + a.z * wcB[2] + a.w * wcB[3];
#pragma unroll
        for (int off = 1; off < 16; off <<= 1) {
            p0 += __shfl_xor(p0, off, 64);
            p1 += __shfl_xor(p1, off, 64);
        }
        int i = row0 + rp * 16 + rq;
        if (i < NR) {
            float z0 = p0 + b0 + gum[2 * i];
            float z1 = p1 + b1 + gum[2 * i + 1];
            bool m = (z0 >= z1);   // argmax tie -> index 0 -> strong
            ((float4*)(outp + (size_t)i * CO))[dq] =
                make_float4(2.f * a.x, 2.f * a.y, 2.f * a.z, 2.f * a.w);
            float4 xm = m ? a : make_float4(0.f, 0.f, 0.f, 0.f);
            ((float4*)(x1m + (size_t)i * CO))[dq] = xm;
            if (dq == 0 && m) { int pos = atomicAdd(&scnt, 1); sl[pos] = i; }
        }
    }
    __syncthreads();
    if (t == 0) sbase = atomicAdd(cnt, scnt);
    __syncthreads();
    if (t < scnt) sids[sbase + t] = sl[t];
}

// ---------------------------------------------------------------------------
// K2: conv2 (64->64) over compacted strong rows. T14 register-staged pipeline:
// per k, next tile's gathers are issued into registers BEFORE compute(k)
// (latency hides under FMAs), then written to LDS after the barrier.
// Invalid/weak slots are plain zero moves — no memory request at all.
// 128 rows/block, single padded gs [128][68] + single Ws -> 50 KB, 2 barriers/k.
// ---------------------------------------------------------------------------
__global__ __launch_bounds__(256, 2)
void k_conv2(const float* __restrict__ x1m, const int* __restrict__ nbr,
             const float* __restrict__ Wdw, const float* __restrict__ bdw,
             const int* __restrict__ sids, const int* __restrict__ cnt,
             float* __restrict__ outp)
{
    const int nstrong = *cnt;
    const int row0 = blockIdx.x * 128;
    if (row0 >= nstrong) return;

    __shared__ float gs[128][68];   // padded: stride 68 -> conflict-free
    __shared__ float Ws[CO * CO];   // 16 KB

    const int t   = threadIdx.x;
    const int dq  = t & 15;
    const int rq  = t >> 4;
    const int dq4 = dq * 4;

    int ssid[8];
#pragma unroll
    for (int p = 0; p < 8; ++p) {
        int rr = row0 + p * 16 + rq;
        ssid[p] = (rr < nstrong) ? sids[rr] : -1;
    }

    int jn[8];
#pragma unroll
    for (int p = 0; p < 8; ++p)
        jn[p] = (ssid[p] >= 0) ? nbr[(size_t)ssid[p] * KK] : NR;

    // prologue: load k=0 tile into regs, W[0] into regs, ids(k=1)
    float4 vbuf[8];
#pragma unroll
    for (int p = 0; p < 8; ++p)
        vbuf[p] = (jn[p] < NR) ? ((const float4*)(x1m + (size_t)jn[p] * CO))[dq]
                               : make_float4(0.f, 0.f, 0.f, 0.f);
    float4 w0r, w1r, w2r, w3r;
    {
        const float4* Wk = (const float4*)Wdw;
        w0r = Wk[t]; w1r = Wk[t + 256]; w2r = Wk[t + 512]; w3r = Wk[t + 768];
    }
#pragma unroll
    for (int p = 0; p < 8; ++p)
        jn[p] = (ssid[p] >= 0) ? nbr[(size_t)ssid[p] * KK + 1] : NR;

    float4 acc[8];
#pragma unroll
    for (int rp = 0; rp < 8; ++rp) acc[rp] = make_float4(0.f, 0.f, 0.f, 0.f);

#pragma unroll 1
    for (int k = 0; k < KK; ++k) {
        __syncthreads();   // previous compute done reading gs/Ws
        // commit staged regs -> LDS (waits on the loads issued last iter,
        // which have had the whole compute phase to land)
#pragma unroll
        for (int p = 0; p < 8; ++p)
            *(float4*)&gs[p * 16 + rq][dq4] = vbuf[p];
        {
            float4* Wv = (float4*)Ws;
            Wv[t] = w0r; Wv[t + 256] = w1r; Wv[t + 512] = w2r; Wv[t + 768] = w3r;
        }
        __syncthreads();   // staging visible

        if (k < KK - 1) {
            // issue next tile's gathers + W prefetch BEFORE compute (T14)
#pragma unroll
            for (int p = 0; p < 8; ++p)
                vbuf[p] = (jn[p] < NR)
                          ? ((const float4*)(x1m + (size_t)jn[p] * CO))[dq]
                          : make_float4(0.f, 0.f, 0.f, 0.f);
            const float4* Wk = (const float4*)(Wdw + (size_t)(k + 1) * CO * CO);
            w0r = Wk[t]; w1r = Wk[t + 256]; w2r = Wk[t + 512]; w3r = Wk[t + 768];
            if (k < KK - 2) {
#pragma unroll
                for (int p = 0; p < 8; ++p)
                    jn[p] = (ssid[p] >= 0) ? nbr[(size_t)ssid[p] * KK + k + 2] : NR;
            }
        }

        // compute k
#pragma unroll
        for (int cq = 0; cq < CO / 4; ++cq) {
            float4 w0 = *(const float4*)&Ws[(cq * 4 + 0) * CO + dq4];
            float4 w1 = *(const float4*)&Ws[(cq * 4 + 1) * CO + dq4];
            float4 w2 = *(const float4*)&Ws[(cq * 4 + 2) * CO + dq4];
            float4 w3 = *(const float4*)&Ws[(cq * 4 + 3) * CO + dq4];
#pragma unroll
            for (int rp = 0; rp < 8; ++rp) {
                float4 g = *(const float4*)&gs[rp * 16 + rq][cq * 4];
                acc[rp].x += g.x * w0.x + g.y * w1.x + g.z * w2.x + g.w * w3.x;
                acc[rp].y += g.x * w0.y + g.y * w1.y + g.z * w2.y + g.w * w3.y;
                acc[rp].z += g.x * w0.z + g.y * w1.z + g.z * w2.z + g.w * w3.z;
                acc[rp].w += g.x * w0.w + g.y * w1.w + g.z * w2.w + g.w * w3.w;
            }
        }
    }

    const float4 bq = ((const float4*)bdw)[dq];
#pragma unroll
    for (int rp = 0; rp < 8; ++rp) {
        int rr = row0 + rp * 16 + rq;
        if (rr < nstrong) {
            int sid = sids[rr];
            float4 xv = ((const float4*)(x1m + (size_t)sid * CO))[dq];
            float4 a = acc[rp];
            ((float4*)(outp + (size_t)sid * CO))[dq] =
                make_float4(a.x + bq.x + xv.x, a.y + bq.y + xv.y,
                            a.z + bq.z + xv.z, a.w + bq.w + xv.w);
        }
    }
}

// ---------------------------------------------------------------------------
extern "C" void kernel_launch(void* const* d_in, const int* in_sizes, int n_in,
                              void* d_out, int out_size, void* d_ws, size_t ws_size,
                              hipStream_t stream)
{
    const float* xF   = (const float*)d_in[0];
    const float* gum  = (const float*)d_in[1];
    const int*   nbr  = (const int*)d_in[2];
    const float* Wch  = (const float*)d_in[3];
    const float* bch  = (const float*)d_in[4];
    const float* Wcls = (const float*)d_in[5];
    const float* bcls = (const float*)d_in[6];
    const float* Wdw  = (const float*)d_in[7];
    const float* bdw  = (const float*)d_in[8];
    // d_in[9] = th (unused by the forward computation)

    float* outp = (float*)d_out;
    char*  ws   = (char*)d_ws;

    // ws layout: [0, 8192) zbufX (64 zero rows x 32 f32) | [8192,8196) cnt |
    //            [8320, 8320+4*NR) sids | then x1m (N*64 f32, 16B aligned)
    float* zbufX = (float*)(ws);
    int*   cnt   = (int*)(ws + 8192);
    int*   sids  = (int*)(ws + 8320);
    float* x1m   = (float*)(ws + 8320 + (size_t)NR * 4);

    hipMemsetAsync(ws, 0, 8320, stream);   // zero buffer + cnt

    hipLaunchKernelGGL(k_conv1, dim3((NR + 127) / 128), dim3(256), 0, stream,
                       xF, gum, nbr, Wch, bch, Wcls, bcls, zbufX,
                       x1m, sids, cnt, outp);
    hipLaunchKernelGGL(k_conv2, dim3((NR + 127) / 128), dim3(256), 0, stream,
                       x1m, nbr, Wdw, bdw, sids, cnt, outp);
}